// Round 9
// baseline (603.657 us; speedup 1.0000x reference)
//
#include <hip/hip_runtime.h>

#define DIM    20
#define NN     200000
#define EE     6400000
#define ITERS  3
#define BLOCK  256

// Bucketing geometry
#define NODES_PER_FINE   64
#define NFINE            3125        // 200000/64 exactly
#define NCOARSE          98          // ceil(200000/2048)
#define FINE_PER_COARSE  32

// p1: exact tiles of 2048 (6.4M/2048 = 3125 blocks, no bounds checks)
#define TILE1            2048
#define IPT1             8           // 2 int4-quads per thread per array

// p2: tiles of 4096 over coarse slack regions
#define TILE             4096
#define IPT              16          // 4 uint4-quads per thread

// slack-region capacities (kept edges = src-depth<=3 ~ 80% = 5.12M)
#define CAP1             57344      // per-coarse: mean 52245, +22sigma; 14 tiles
#define NT2P             14
#define CAP2             2048       // per-fine: mean 1638, +10sigma
#define PIPT             8          // CAP2/BLOCK

#define XSTRIDE          21         // LDS x row stride (gcd(21,32)=1 -> conflict-free)

typedef unsigned int u32;

// ---------------- kdep: per-block depth histogram ----------------
__global__ __launch_bounds__(BLOCK) void kdep(const int* __restrict__ depth,
                                              int* __restrict__ dcnt) {
    __shared__ u32 dh[5];
    int tid = threadIdx.x;
    if (tid < 5) dh[tid] = 0;
    __syncthreads();
    for (int n = blockIdx.x * BLOCK + tid; n < NN; n += gridDim.x * BLOCK)
        atomicAdd(&dh[depth[n]], 1u);
    __syncthreads();
    if (tid < 5) dcnt[tid * 256 + blockIdx.x] = (int)dh[tid];   // depth-major
}

// ---------------- k2: scan depth counts -> perm bases + cum ----------------
__global__ __launch_bounds__(BLOCK) void k2_scan(const int* __restrict__ dcnt,
                                                 int* __restrict__ dbase,
                                                 int* __restrict__ cum) {
    __shared__ int wsum[4];
    __shared__ int sdb[1281];
    int tid = threadIdx.x;
    int lane = tid & 63, wid = tid >> 6;
    const int CH2 = 5;
    int loc[CH2];
    int base = tid * CH2;
    int s = 0;
    #pragma unroll
    for (int j = 0; j < CH2; ++j) { int v = dcnt[base + j]; loc[j] = v; s += v; }
    int incl = s;
    #pragma unroll
    for (int off = 1; off < 64; off <<= 1) {
        int t = __shfl_up(incl, off, 64);
        if (lane >= off) incl += t;
    }
    if (lane == 63) wsum[wid] = incl;
    __syncthreads();
    int woff = 0;
    for (int w = 0; w < wid; ++w) woff += wsum[w];
    int run = woff + incl - s;
    #pragma unroll
    for (int j = 0; j < CH2; ++j) {
        sdb[base + j]   = run;
        dbase[base + j] = run;
        run += loc[j];
    }
    if (tid == 255) sdb[1280] = run;       // == NN
    __syncthreads();
    if (tid < 5) cum[tid] = sdb[(tid + 1) * 256];   // cum[d] = #nodes depth <= d
}

// ---------------- KD: scatter perm (depth-ordered compact renumbering) ----------------
__global__ __launch_bounds__(BLOCK) void kd_scatter(const int* __restrict__ depth,
                                                    const int* __restrict__ dbase,
                                                    int* __restrict__ perm) {
    __shared__ u32 dh[5];
    int tid = threadIdx.x;
    if (tid < 5) dh[tid] = 0;
    __syncthreads();
    for (int n = blockIdx.x * BLOCK + tid; n < NN; n += gridDim.x * BLOCK) {
        int d = depth[n];
        u32 r = atomicAdd(&dh[d], 1u);
        perm[n] = dbase[d * 256 + blockIdx.x] + (int)r;
    }
}

// ---------------- setup: cursors + h->bf16 conversion (pid-compacted rows) ----------------
__device__ __forceinline__ u32 pack_bf16x2(float a, float b) {
    u32 ua = __float_as_uint(a);
    u32 ub = __float_as_uint(b);
    ua = (ua + 0x7FFFu + ((ua >> 16) & 1u)) >> 16;
    ub = (ub + 0x7FFFu + ((ub >> 16) & 1u)) & 0xFFFF0000u;
    return ua | ub;
}

__global__ __launch_bounds__(BLOCK) void setup(const float* __restrict__ h,
                                               const int* __restrict__ depth,
                                               const int* __restrict__ perm,
                                               u32* __restrict__ hbA,
                                               u32* __restrict__ hbC,
                                               int* __restrict__ coarse_cursor,
                                               int* __restrict__ fine_cursor,
                                               int* __restrict__ gcur) {
    int g = blockIdx.x * BLOCK + threadIdx.x;          // grid = NN*8 threads
    if (g < NCOARSE) coarse_cursor[g] = g * CAP1;
    if (g < NFINE)   fine_cursor[g]   = g * CAP2;
    if (g == 0) *gcur = 0;
    int node = g >> 3, s = g & 7;
    if (depth[node] > ITERS) return;                   // depth-4 rows never read
    int pid = perm[node];
    float2 f = *(const float2*)(h + (size_t)node * DIM + s * 2);
    hbA[(size_t)pid * 8 + s] = pack_bf16x2(f.x, f.y);
    if (s < 2) {
        float2 fc = *(const float2*)(h + (size_t)node * DIM + 16 + s * 2);
        hbC[(size_t)pid * 2 + s] = pack_bf16x2(fc.x, fc.y);
    }
}

// ---------------- P1: edges -> 98 coarse regions; perm gather + dead-src drop ----------------
// item u32 = dlow(11) | pid<<11 (18)
__global__ __launch_bounds__(BLOCK) void p1_split(const int* __restrict__ esrc,
                                                  const int* __restrict__ edst,
                                                  const int* __restrict__ perm,
                                                  const int* __restrict__ cum,
                                                  int* __restrict__ coarse_cursor,
                                                  u32* __restrict__ buf1) {
    __shared__ u32 hist[NCOARSE];
    __shared__ u32 lbase[NCOARSE];
    __shared__ u32 gbase[NCOARSE];
    __shared__ u32 lout[TILE1];
    int tid = threadIdx.x;
    int start = blockIdx.x * TILE1;
    if (tid < NCOARSE) hist[tid] = 0;
    __syncthreads();
    const u32 c3 = (u32)cum[3];            // #nodes with depth <= 3

    int4 d4[2], s4[2];
    #pragma unroll
    for (int q = 0; q < 2; ++q) {
        int e4 = start + (q * BLOCK + tid) * 4;
        d4[q] = *(const int4*)(edst + e4);
        s4[q] = *(const int4*)(esrc + e4);
    }
    u32 pid[IPT1];
    pid[0] = (u32)perm[s4[0].x]; pid[1] = (u32)perm[s4[0].y];
    pid[2] = (u32)perm[s4[0].z]; pid[3] = (u32)perm[s4[0].w];
    pid[4] = (u32)perm[s4[1].x]; pid[5] = (u32)perm[s4[1].y];
    pid[6] = (u32)perm[s4[1].z]; pid[7] = (u32)perm[s4[1].w];
    asm volatile("" :: "v"(pid[0]), "v"(pid[1]), "v"(pid[2]), "v"(pid[3]),
                       "v"(pid[4]), "v"(pid[5]), "v"(pid[6]), "v"(pid[7]));
    int dd[IPT1];
    dd[0]=d4[0].x; dd[1]=d4[0].y; dd[2]=d4[0].z; dd[3]=d4[0].w;
    dd[4]=d4[1].x; dd[5]=d4[1].y; dd[6]=d4[1].z; dd[7]=d4[1].w;

    u32 rank[IPT1];
    #pragma unroll
    for (int k = 0; k < IPT1; ++k)
        if (pid[k] < c3) rank[k] = atomicAdd(&hist[(u32)dd[k] >> 11], 1u);
    __syncthreads();

    // scan the 98-bin histogram (wave 0) -> LDS layout bases
    if (tid < 64) {
        u32 a = hist[tid];
        u32 b = (tid + 64 < NCOARSE) ? hist[tid + 64] : 0u;
        u32 ia = a, ib = b;
        #pragma unroll
        for (int off = 1; off < 64; off <<= 1) {
            u32 ta = (u32)__shfl_up((int)ia, off, 64);
            u32 tb = (u32)__shfl_up((int)ib, off, 64);
            if (tid >= off) { ia += ta; ib += tb; }
        }
        u32 totA = (u32)__shfl((int)ia, 63, 64);
        lbase[tid] = ia - a;
        if (tid + 64 < NCOARSE) lbase[tid + 64] = totA + ib - b;
    }
    __syncthreads();
    if (tid < NCOARSE) {
        u32 cq = hist[tid];
        gbase[tid] = cq ? (u32)atomicAdd((u32*)&coarse_cursor[tid], cq) : 0u;
    }
    #pragma unroll
    for (int k = 0; k < IPT1; ++k)
        if (pid[k] < c3)
            lout[lbase[(u32)dd[k] >> 11] + rank[k]] = ((u32)dd[k] & 2047u) | (pid[k] << 11);
    __syncthreads();
    int wid = tid >> 6, lane = tid & 63;
    for (int b = wid; b < NCOARSE; b += 4) {
        u32 cq = hist[b], lb = lbase[b], gb = gbase[b];
        for (u32 i = lane; i < cq; i += 64)
            buf1[gb + i] = lout[lb + i];
    }
}

// ---------------- P2: coarse -> fine regions, LDS-staged coalesced flush ----------------
// item u32 = ln(6) | pid<<6 (18)
__global__ __launch_bounds__(BLOCK) void p2_split(const u32* __restrict__ buf1,
                                                  const int* __restrict__ coarse_cursor,
                                                  int* __restrict__ fine_cursor,
                                                  u32* __restrict__ buf2) {
    int bid = blockIdx.x;
    int c = bid / NT2P, t = bid - c * NT2P;
    int base  = c * CAP1;
    int end   = coarse_cursor[c];                 // base + kept count
    int start = base + t * TILE;
    if (start >= end) return;

    __shared__ u32 hist[FINE_PER_COARSE];
    __shared__ u32 lbase[FINE_PER_COARSE];
    __shared__ u32 gbase[FINE_PER_COARSE];
    __shared__ u32 lout[TILE];
    int tid = threadIdx.x;
    if (tid < FINE_PER_COARSE) hist[tid] = 0;
    __syncthreads();

    u32 w[IPT];
    #pragma unroll
    for (int q = 0; q < 4; ++q) {
        int i4 = start + (q * BLOCK + tid) * 4;
        if (i4 + 3 < end) {
            uint4 v = *(const uint4*)(buf1 + i4);
            w[q * 4 + 0] = v.x; w[q * 4 + 1] = v.y;
            w[q * 4 + 2] = v.z; w[q * 4 + 3] = v.w;
        } else {
            #pragma unroll
            for (int j = 0; j < 4; ++j) {
                int i = i4 + j;
                w[q * 4 + j] = (i < end) ? buf1[i] : 0xFFFFFFFFu;
            }
        }
    }
    u32 rank[IPT];
    #pragma unroll
    for (int k = 0; k < IPT; ++k)
        if (w[k] != 0xFFFFFFFFu)
            rank[k] = atomicAdd(&hist[(w[k] & 2047u) >> 6], 1u);
    __syncthreads();

    if (tid < 32) {
        u32 a = hist[tid], ia = a;
        #pragma unroll
        for (int off = 1; off < 32; off <<= 1) {
            u32 ta = (u32)__shfl_up((int)ia, off, 32);
            if (tid >= off) ia += ta;
        }
        lbase[tid] = ia - a;
        int f = c * FINE_PER_COARSE + tid;
        gbase[tid] = a ? (u32)atomicAdd((u32*)&fine_cursor[f], a) : 0u;
    }
    __syncthreads();
    #pragma unroll
    for (int k = 0; k < IPT; ++k)
        if (w[k] != 0xFFFFFFFFu)
            lout[lbase[(w[k] & 2047u) >> 6] + rank[k]] = (w[k] & 63u) | ((w[k] >> 11) << 6);
    __syncthreads();
    int wid = tid >> 6, lane = tid & 63;
    for (int b = wid; b < FINE_PER_COARSE; b += 4) {
        u32 cq = hist[b], lb = lbase[b], gb = gbase[b];
        for (u32 i = lane; i < cq; i += 64)
            buf2[gb + i] = lout[lb + i];
    }
}

// ---------------- shared device helpers for gather/GRU ----------------

__device__ __forceinline__ float bl(u32 w) { return __uint_as_float(w << 16); }
__device__ __forceinline__ float bh(u32 w) { return __uint_as_float(w & 0xFFFF0000u); }

__device__ __forceinline__ void acc_half(float* xa, float* xc, uint4 a, u32 c) {
    xa[0]+=bl(a.x); xa[1]+=bh(a.x);
    xa[2]+=bl(a.y); xa[3]+=bh(a.y);
    xa[4]+=bl(a.z); xa[5]+=bh(a.z);
    xa[6]+=bl(a.w); xa[7]+=bh(a.w);
    xc[0]+=bl(c);   xc[1]+=bh(c);
}

__device__ __forceinline__ float fast_sigmoid(float t) {
    return 1.0f / (1.0f + __expf(-t));
}
__device__ __forceinline__ float fast_tanh(float t) {
    t = fminf(fmaxf(t, -15.0f), 15.0f);
    float e2 = __expf(2.0f * t);
    return (e2 - 1.0f) / (e2 + 1.0f);
}

// GRU for 64 nodes on wave 0 (tid<64); x from xl; hb write gated by pid < cumNext
__device__ __forceinline__ void gru_body(
    int u, int pid, int tid, const float* xl,
    const float* __restrict__ h_in, float* __restrict__ h_out,
    u32* __restrict__ hbA_out, u32* __restrict__ hbC_out,
    int cumNext, int isFinal,
    const float* __restrict__ Wz, const float* __restrict__ bWz,
    const float* __restrict__ Uz, const float* __restrict__ bUz,
    const float* __restrict__ Wr, const float* __restrict__ bWr,
    const float* __restrict__ Ur, const float* __restrict__ bUr,
    const float* __restrict__ Wh, const float* __restrict__ bWh,
    const float* __restrict__ Uh, const float* __restrict__ bUh)
{
    float x[DIM], h[DIM];
    #pragma unroll
    for (int k = 0; k < DIM; ++k) x[k] = xl[tid * XSTRIDE + k];
    {
        const float4* hv = (const float4*)(h_in + (size_t)u * DIM);
        float4 a0 = hv[0], a1 = hv[1], a2 = hv[2], a3 = hv[3], a4 = hv[4];
        h[0]=a0.x; h[1]=a0.y; h[2]=a0.z; h[3]=a0.w;
        h[4]=a1.x; h[5]=a1.y; h[6]=a1.z; h[7]=a1.w;
        h[8]=a2.x; h[9]=a2.y; h[10]=a2.z; h[11]=a2.w;
        h[12]=a3.x; h[13]=a3.y; h[14]=a3.z; h[15]=a3.w;
        h[16]=a4.x; h[17]=a4.y; h[18]=a4.z; h[19]=a4.w;
    }

    float z[DIM], rh[DIM];
    #pragma unroll
    for (int j = 0; j < DIM; ++j) {
        float sz = bWz[j] + bUz[j];
        float sr = bWr[j] + bUr[j];
        #pragma unroll
        for (int k = 0; k < DIM; ++k) {
            sz += x[k] * Wz[j * DIM + k];
            sz += h[k] * Uz[j * DIM + k];
            sr += x[k] * Wr[j * DIM + k];
            sr += h[k] * Ur[j * DIM + k];
        }
        z[j]  = fast_sigmoid(sz);
        rh[j] = fast_sigmoid(sr) * h[j];
    }

    float o[DIM];
    #pragma unroll
    for (int j = 0; j < DIM; ++j) {
        float sh = bWh[j] + bUh[j];
        #pragma unroll
        for (int k = 0; k < DIM; ++k) {
            sh += x[k]  * Wh[j * DIM + k];
            sh += rh[k] * Uh[j * DIM + k];
        }
        float hc = fast_tanh(sh);
        o[j] = z[j] * h[j] + (1.0f - z[j]) * hc;
    }

    {
        float4* o4 = (float4*)(h_out + (size_t)u * DIM);
        o4[0] = make_float4(o[0],  o[1],  o[2],  o[3]);
        o4[1] = make_float4(o[4],  o[5],  o[6],  o[7]);
        o4[2] = make_float4(o[8],  o[9],  o[10], o[11]);
        o4[3] = make_float4(o[12], o[13], o[14], o[15]);
        o4[4] = make_float4(o[16], o[17], o[18], o[19]);
    }
    if (!isFinal && pid < cumNext) {                 // only rows read next iteration
        u32* rowA = hbA_out + (size_t)pid * 8;
        uint4 wA0 = make_uint4(pack_bf16x2(o[0], o[1]),   pack_bf16x2(o[2], o[3]),
                               pack_bf16x2(o[4], o[5]),   pack_bf16x2(o[6], o[7]));
        uint4 wA1 = make_uint4(pack_bf16x2(o[8], o[9]),   pack_bf16x2(o[10], o[11]),
                               pack_bf16x2(o[12], o[13]), pack_bf16x2(o[14], o[15]));
        *(uint4*)rowA       = wA0;
        *(uint4*)(rowA + 4) = wA1;
        *(uint2*)(hbC_out + (size_t)pid * 2) =
            make_uint2(pack_bf16x2(o[16], o[17]), pack_bf16x2(o[18], o[19]));
    }
}

// ---------------- PB_GRU: sort fine bucket + it0 gather (from LDS) + it0 GRU, fused ----------------
__global__ __launch_bounds__(BLOCK) void pb_gru(
    const u32* __restrict__ buf2, const int* __restrict__ fine_cursor,
    const int* __restrict__ cum, int* __restrict__ gcur,
    int* __restrict__ ptr, u32* __restrict__ cnt3, u32* __restrict__ ssrc,
    const u32* __restrict__ hbA_in, const u32* __restrict__ hbC_in,
    u32* __restrict__ hbA_out, u32* __restrict__ hbC_out,
    const float* __restrict__ h_in, float* __restrict__ h_out,
    const int* __restrict__ depth, const int* __restrict__ perm,
    const float* __restrict__ Wz, const float* __restrict__ bWz,
    const float* __restrict__ Uz, const float* __restrict__ bUz,
    const float* __restrict__ Wr, const float* __restrict__ bWr,
    const float* __restrict__ Ur, const float* __restrict__ bUr,
    const float* __restrict__ Wh, const float* __restrict__ bWh,
    const float* __restrict__ Uh, const float* __restrict__ bUh)
{
    __shared__ u32 hist[512];
    __shared__ u32 ebase[512];
    __shared__ u32 lout[CAP2];
    __shared__ u32 wsum[4];
    __shared__ int slo;
    __shared__ float xl[64 * XSTRIDE];               // 5376 B
    int tid = threadIdx.x;
    int f = blockIdx.x;
    int base = f * CAP2;
    int end  = fine_cursor[f];
    int cnt  = end - base;
    u32 c0 = (u32)cum[0], c1 = (u32)cum[1], c2 = (u32)cum[2];
    hist[tid] = 0; hist[tid + 256] = 0;
    __syncthreads();

    // ---- sort phase (counting sort on (node, class)) ----
    u32 w[PIPT];
    #pragma unroll
    for (int q = 0; q < 2; ++q) {
        int i4 = base + (q * BLOCK + tid) * 4;
        if (i4 + 3 < end) {
            uint4 v = *(const uint4*)(buf2 + i4);
            w[q * 4 + 0] = v.x; w[q * 4 + 1] = v.y;
            w[q * 4 + 2] = v.z; w[q * 4 + 3] = v.w;
        } else {
            #pragma unroll
            for (int j = 0; j < 4; ++j) {
                int i = i4 + j;
                w[q * 4 + j] = (i < end) ? buf2[i] : 0xFFFFFFFFu;
            }
        }
    }
    u32 key[PIPT], rank[PIPT];
    #pragma unroll
    for (int k = 0; k < PIPT; ++k) {
        if (w[k] != 0xFFFFFFFFu) {
            u32 pid = w[k] >> 6;
            u32 cls = (u32)(pid >= c0) + (u32)(pid >= c1) + (u32)(pid >= c2);
            key[k]  = (w[k] & 63u) * 8u + cls;
            rank[k] = atomicAdd(&hist[key[k]], 1u);
        }
    }
    if (tid == 0) slo = atomicAdd(gcur, cnt);     // reserve packed output space
    __syncthreads();
    {
        u32 s0 = hist[2 * tid], s1 = hist[2 * tid + 1];
        u32 s = s0 + s1;
        int lane = tid & 63, wid = tid >> 6;
        u32 incl = s;
        #pragma unroll
        for (int off = 1; off < 64; off <<= 1) {
            u32 t = __shfl_up((int)incl, off, 64);
            if (lane >= off) incl += t;
        }
        if (lane == 63) wsum[wid] = incl;
        __syncthreads();
        u32 woff = 0;
        for (int w2 = 0; w2 < wid; ++w2) woff += wsum[w2];
        u32 excl = woff + incl - s;
        ebase[2 * tid]     = excl;
        ebase[2 * tid + 1] = excl + s0;
    }
    __syncthreads();
    int lo = slo;
    if (tid < NODES_PER_FINE) {
        u32 base0 = ebase[tid * 8];
        u32 cc1 = ebase[tid * 8 + 2] - base0;
        u32 cc2 = ebase[tid * 8 + 3] - base0;
        u32 cc3 = ebase[tid * 8 + 4] - base0;
        int u = f * NODES_PER_FINE + tid;
        ptr[u]  = lo + (int)base0;
        cnt3[u] = cc1 | (cc2 << 10) | (cc3 << 20);
    }
    #pragma unroll
    for (int k = 0; k < PIPT; ++k) {
        if (w[k] != 0xFFFFFFFFu) lout[ebase[key[k]] + rank[k]] = w[k] >> 6;
    }
    __syncthreads();
    // flush packed list for it1/it2
    for (int j = tid; j < cnt; j += BLOCK) ssrc[lo + j] = lout[j];

    // ---- it0 gather phase: indices straight from LDS lout ----
    int t = tid & 7, team = tid >> 3;                // 32 teams of 8 lanes
    int r = t >> 1, q = t & 1;                       // 4 row slots x 2 half-rows
    #pragma unroll
    for (int rep = 0; rep < 2; ++rep) {
        int nl = team + rep * 32;
        int u = f * NODES_PER_FINE + nl;
        if (depth[u] <= ITERS) {
            int b0 = (int)ebase[nl * 8];
            int d  = (int)(ebase[nl * 8 + 4] - ebase[nl * 8]);   // class<=3 count

            float xa[8], xc[2];
            #pragma unroll
            for (int k = 0; k < 8; ++k) xa[k] = 0.0f;
            xc[0] = 0.0f; xc[1] = 0.0f;

            int e = r;
            for (; e + 12 < d; e += 16) {            // 4 rows in flight per lane
                u32 p0 = lout[b0 + e];
                u32 p1 = lout[b0 + e + 4];
                u32 p2 = lout[b0 + e + 8];
                u32 p3 = lout[b0 + e + 12];
                uint4 a0 = *(const uint4*)(hbA_in + (size_t)p0 * 8 + q * 4);
                uint4 a1 = *(const uint4*)(hbA_in + (size_t)p1 * 8 + q * 4);
                uint4 a2 = *(const uint4*)(hbA_in + (size_t)p2 * 8 + q * 4);
                uint4 a3 = *(const uint4*)(hbA_in + (size_t)p3 * 8 + q * 4);
                u32 cc0 = hbC_in[(size_t)p0 * 2 + q];
                u32 cc1 = hbC_in[(size_t)p1 * 2 + q];
                u32 cc2 = hbC_in[(size_t)p2 * 2 + q];
                u32 cc3 = hbC_in[(size_t)p3 * 2 + q];
                acc_half(xa, xc, a0, cc0);
                acc_half(xa, xc, a1, cc1);
                acc_half(xa, xc, a2, cc2);
                acc_half(xa, xc, a3, cc3);
            }
            for (; e + 4 < d; e += 8) {
                u32 p0 = lout[b0 + e];
                u32 p1 = lout[b0 + e + 4];
                uint4 a0 = *(const uint4*)(hbA_in + (size_t)p0 * 8 + q * 4);
                uint4 a1 = *(const uint4*)(hbA_in + (size_t)p1 * 8 + q * 4);
                u32 cc0 = hbC_in[(size_t)p0 * 2 + q];
                u32 cc1 = hbC_in[(size_t)p1 * 2 + q];
                acc_half(xa, xc, a0, cc0);
                acc_half(xa, xc, a1, cc1);
            }
            if (e < d) {
                u32 p0 = lout[b0 + e];
                uint4 a0 = *(const uint4*)(hbA_in + (size_t)p0 * 8 + q * 4);
                u32 cc0 = hbC_in[(size_t)p0 * 2 + q];
                acc_half(xa, xc, a0, cc0);
            }
            #pragma unroll
            for (int k = 0; k < 8; ++k) {
                xa[k] += __shfl_xor(xa[k], 2, 64);
                xa[k] += __shfl_xor(xa[k], 4, 64);
            }
            xc[0] += __shfl_xor(xc[0], 2, 64); xc[0] += __shfl_xor(xc[0], 4, 64);
            xc[1] += __shfl_xor(xc[1], 2, 64); xc[1] += __shfl_xor(xc[1], 4, 64);

            float* xr = xl + nl * XSTRIDE;
            if (t == 0) {                            // q=0: dims 0-7, 16,17
                #pragma unroll
                for (int k = 0; k < 8; ++k) xr[k] = xa[k];
                xr[16] = xc[0]; xr[17] = xc[1];
            } else if (t == 1) {                     // q=1: dims 8-15, 18,19
                #pragma unroll
                for (int k = 0; k < 8; ++k) xr[8 + k] = xa[k];
                xr[18] = xc[0]; xr[19] = xc[1];
            }
        }
    }
    __syncthreads();
    if (tid >= 64) return;                           // waves 1-3 retire

    // ---- it0 GRU phase ----
    int u = f * NODES_PER_FINE + tid;
    if (depth[u] > ITERS) return;                    // not final: no zero-fill
    int pid = perm[u];
    gru_body(u, pid, tid, xl, h_in, h_out, hbA_out, hbC_out, (int)c2, 0,
             Wz, bWz, Uz, bUz, Wr, bWr, Ur, bUr, Wh, bWh, Uh, bUh);
}

// ---------------- fused iteration (it1/it2): gather from global ssrc + GRU ----------------

__global__ __launch_bounds__(BLOCK) void grnn_iter(
    const u32* __restrict__ hbA_in, const u32* __restrict__ hbC_in,
    u32* __restrict__ hbA_out, u32* __restrict__ hbC_out,
    const float* __restrict__ h_in, float* __restrict__ h_out,
    const int* __restrict__ depth, const int* __restrict__ perm,
    const int* __restrict__ cum,
    const int* __restrict__ ptr, const u32* __restrict__ cnt3,
    const u32* __restrict__ ssrc,
    const float* __restrict__ Wz, const float* __restrict__ bWz,
    const float* __restrict__ Uz, const float* __restrict__ bUz,
    const float* __restrict__ Wr, const float* __restrict__ bWr,
    const float* __restrict__ Ur, const float* __restrict__ bUr,
    const float* __restrict__ Wh, const float* __restrict__ bWh,
    const float* __restrict__ Uh, const float* __restrict__ bUh,
    int lim, int cumIdx, int shift, int isFinal)
{
    __shared__ float xl[64 * XSTRIDE];               // 5376 B
    int tid = threadIdx.x;
    int t = tid & 7, team = tid >> 3;                // 32 teams of 8 lanes
    int r = t >> 1, q = t & 1;                       // 4 row slots x 2 half-rows

    #pragma unroll
    for (int rep = 0; rep < 2; ++rep) {
        int nl = team + rep * 32;
        int u = blockIdx.x * 64 + nl;
        if (depth[u] <= lim) {
            int p = ptr[u];
            int d = (int)((cnt3[u] >> shift) & 1023u);

            float xa[8], xc[2];
            #pragma unroll
            for (int k = 0; k < 8; ++k) xa[k] = 0.0f;
            xc[0] = 0.0f; xc[1] = 0.0f;

            int e = r;
            for (; e + 12 < d; e += 16) {            // 4 rows in flight per lane
                u32 p0 = ssrc[p + e];
                u32 p1 = ssrc[p + e + 4];
                u32 p2 = ssrc[p + e + 8];
                u32 p3 = ssrc[p + e + 12];
                uint4 a0 = *(const uint4*)(hbA_in + (size_t)p0 * 8 + q * 4);
                uint4 a1 = *(const uint4*)(hbA_in + (size_t)p1 * 8 + q * 4);
                uint4 a2 = *(const uint4*)(hbA_in + (size_t)p2 * 8 + q * 4);
                uint4 a3 = *(const uint4*)(hbA_in + (size_t)p3 * 8 + q * 4);
                u32 cc0 = hbC_in[(size_t)p0 * 2 + q];
                u32 cc1 = hbC_in[(size_t)p1 * 2 + q];
                u32 cc2 = hbC_in[(size_t)p2 * 2 + q];
                u32 cc3 = hbC_in[(size_t)p3 * 2 + q];
                acc_half(xa, xc, a0, cc0);
                acc_half(xa, xc, a1, cc1);
                acc_half(xa, xc, a2, cc2);
                acc_half(xa, xc, a3, cc3);
            }
            for (; e + 4 < d; e += 8) {
                u32 p0 = ssrc[p + e];
                u32 p1 = ssrc[p + e + 4];
                uint4 a0 = *(const uint4*)(hbA_in + (size_t)p0 * 8 + q * 4);
                uint4 a1 = *(const uint4*)(hbA_in + (size_t)p1 * 8 + q * 4);
                u32 cc0 = hbC_in[(size_t)p0 * 2 + q];
                u32 cc1 = hbC_in[(size_t)p1 * 2 + q];
                acc_half(xa, xc, a0, cc0);
                acc_half(xa, xc, a1, cc1);
            }
            if (e < d) {
                u32 p0 = ssrc[p + e];
                uint4 a0 = *(const uint4*)(hbA_in + (size_t)p0 * 8 + q * 4);
                u32 cc0 = hbC_in[(size_t)p0 * 2 + q];
                acc_half(xa, xc, a0, cc0);
            }
            #pragma unroll
            for (int k = 0; k < 8; ++k) {
                xa[k] += __shfl_xor(xa[k], 2, 64);
                xa[k] += __shfl_xor(xa[k], 4, 64);
            }
            xc[0] += __shfl_xor(xc[0], 2, 64); xc[0] += __shfl_xor(xc[0], 4, 64);
            xc[1] += __shfl_xor(xc[1], 2, 64); xc[1] += __shfl_xor(xc[1], 4, 64);

            float* xr = xl + nl * XSTRIDE;
            if (t == 0) {
                #pragma unroll
                for (int k = 0; k < 8; ++k) xr[k] = xa[k];
                xr[16] = xc[0]; xr[17] = xc[1];
            } else if (t == 1) {
                #pragma unroll
                for (int k = 0; k < 8; ++k) xr[8 + k] = xa[k];
                xr[18] = xc[0]; xr[19] = xc[1];
            }
        }
    }
    __syncthreads();
    if (tid >= 64) return;                           // waves 1-3 retire

    int u = blockIdx.x * 64 + tid;
    if (depth[u] > lim) {
        if (isFinal) {
            float4 z4 = make_float4(0.f, 0.f, 0.f, 0.f);
            float4* o4 = (float4*)(h_out + (size_t)u * DIM);
            #pragma unroll
            for (int qq = 0; qq < 5; ++qq) o4[qq] = z4;
        }
        return;
    }
    int pid = perm[u];
    gru_body(u, pid, tid, xl, h_in, h_out, hbA_out, hbC_out, cum[cumIdx], isFinal,
             Wz, bWz, Uz, bUz, Wr, bWr, Ur, bUr, Wh, bWh, Uh, bUh);
}

// ---------------- launch ----------------

extern "C" void kernel_launch(void* const* d_in, const int* in_sizes, int n_in,
                              void* d_out, int out_size, void* d_ws, size_t ws_size,
                              hipStream_t stream) {
    const float* h0    = (const float*)d_in[0];
    const int*   depth = (const int*)d_in[1];
    const int*   esrc  = (const int*)d_in[2];
    const int*   edst  = (const int*)d_in[3];
    const float* Wz  = (const float*)d_in[4];  const float* bWz = (const float*)d_in[5];
    const float* Uz  = (const float*)d_in[6];  const float* bUz = (const float*)d_in[7];
    const float* Wr  = (const float*)d_in[8];  const float* bWr = (const float*)d_in[9];
    const float* Ur  = (const float*)d_in[10]; const float* bUr = (const float*)d_in[11];
    const float* Wh  = (const float*)d_in[12]; const float* bWh = (const float*)d_in[13];
    const float* Uh  = (const float*)d_in[14]; const float* bUh = (const float*)d_in[15];
    float* out = (float*)d_out;

    // workspace layout (int32 units)
    int* W = (int*)d_ws;
    int*  dcnt          = W + 0;                   // 1280 (5*256, depth-major)
    int*  dbase         = W + 1280;                // 1280
    int*  cum           = W + 2560;                // 8
    int*  gcur          = W + 2568;                // 1 (+pad)
    int*  coarse_cursor = W + 2576;                // 98 (+pad)
    int*  fine_cursor   = W + 2688;                // 3125 (+pad)
    int*  ptr           = W + 5824;                // NN
    u32*  cnt3          = (u32*)(W + 205824);      // NN
    int*  perm          = W + 405824;              // NN
    u32*  buf1          = (u32*)(W + 605824);      // 98*CAP1 = 5,619,712 (later packed ssrc)
    u32*  buf2          = buf1 + (size_t)NCOARSE * CAP1;   // 3125*CAP2 = 6,400,000
    float* h1           = (float*)(buf2 + (size_t)NFINE * CAP2); // NN*DIM
    u32*  hbA0          = (u32*)(h1 + (size_t)NN * DIM);  // NN*8 (pid-compacted rows)
    u32*  hbC0          = hbA0 + (size_t)NN * 8;          // NN*2
    u32*  hbA1          = hbC0 + (size_t)NN * 2;          // NN*8
    u32*  hbC1          = hbA1 + (size_t)NN * 8;          // NN*2
    u32*  ssrc          = buf1;                    // packed output of pb (pids)

    kdep      <<<256, BLOCK, 0, stream>>>(depth, dcnt);
    k2_scan   <<<1,   BLOCK, 0, stream>>>(dcnt, dbase, cum);
    kd_scatter<<<256, BLOCK, 0, stream>>>(depth, dbase, perm);
    setup     <<<(NN * 8) / BLOCK, BLOCK, 0, stream>>>(h0, depth, perm, hbA0, hbC0,
                                                       coarse_cursor, fine_cursor, gcur);
    p1_split  <<<EE / TILE1, BLOCK, 0, stream>>>(esrc, edst, perm, cum, coarse_cursor, buf1);
    p2_split  <<<NCOARSE * NT2P, BLOCK, 0, stream>>>(buf1, coarse_cursor, fine_cursor, buf2);

    // pb + it0 fused: sort, write ssrc/ptr/cnt3 for it1/2, gather from LDS, GRU
    pb_gru    <<<NFINE, BLOCK, 0, stream>>>(buf2, fine_cursor, cum, gcur, ptr, cnt3, ssrc,
        hbA0, hbC0, hbA1, hbC1, h0, h1, depth, perm,
        Wz, bWz, Uz, bUz, Wr, bWr, Ur, bUr, Wh, bWh, Uh, bUh);

    // it1: lim=2, shift=10 (c_le2); reads hb1 (3.84MB hot -> L2-fits), writes hb0 for pid<cum[1]
    grnn_iter<<<NN / 64, BLOCK, 0, stream>>>(hbA1, hbC1, hbA0, hbC0, h1, h1,
        depth, perm, cum, ptr, cnt3, ssrc,
        Wz, bWz, Uz, bUz, Wr, bWr, Ur, bUr, Wh, bWh, Uh, bUh, 2, 1, 10, 0);
    // it2: lim=1, shift=0 (c_le1); final -> write out, zero inactive
    grnn_iter<<<NN / 64, BLOCK, 0, stream>>>(hbA0, hbC0, hbA1, hbC1, h1, out,
        depth, perm, cum, ptr, cnt3, ssrc,
        Wz, bWz, Uz, bUz, Wr, bWr, Ur, bUr, Wh, bWh, Uh, bUh, 1, 0, 0, 1);
}

// Round 10
// 481.868 us; speedup vs baseline: 1.2527x; 1.2527x over previous
//
#include <hip/hip_runtime.h>

#define DIM    20
#define NN     200000
#define EE     6400000
#define ITERS  3
#define BLOCK  256

// Bucketing geometry
#define NODES_PER_FINE   64
#define NFINE            3125        // 200000/64 exactly
#define NCOARSE          98          // ceil(200000/2048)
#define FINE_PER_COARSE  32

// p1: exact tiles of 2048 (6.4M/2048 = 3125 blocks, no bounds checks)
#define TILE1            2048
#define IPT1             8           // 2 int4-quads per thread per array

// p2: tiles of 4096 over coarse slack regions
#define TILE             4096
#define IPT              16          // 4 uint4-quads per thread

// slack-region capacities (kept edges = src-depth<=3 ~ 80% = 5.12M)
#define CAP1             57344      // per-coarse: mean 52245, +22sigma; 14 tiles
#define NT2P             14
#define CAP2             2048       // per-fine: mean 1638, +10sigma
#define PIPT             8          // CAP2/BLOCK (2 quads exactly)

#define XSTRIDE          21         // LDS x row stride (gcd(21,32)=1 -> conflict-free)

typedef unsigned int u32;

// ---------------- setup: cursors + class table + h->bf16 conversion, one launch ----------------
__device__ __forceinline__ u32 pack_bf16x2(float a, float b) {
    u32 ua = __float_as_uint(a);
    u32 ub = __float_as_uint(b);
    ua = (ua + 0x7FFFu + ((ua >> 16) & 1u)) >> 16;
    ub = (ub + 0x7FFFu + ((ub >> 16) & 1u)) & 0xFFFF0000u;
    return ua | ub;
}

__global__ __launch_bounds__(BLOCK) void setup(const float* __restrict__ h,
                                               const int* __restrict__ depth,
                                               u32* __restrict__ hbA,
                                               u32* __restrict__ hbC,
                                               u32* __restrict__ CT,
                                               int* __restrict__ coarse_cursor,
                                               int* __restrict__ fine_cursor,
                                               int* __restrict__ gcur) {
    int g = blockIdx.x * BLOCK + threadIdx.x;          // grid = NN*8 threads
    if (g < NCOARSE) coarse_cursor[g] = g * CAP1;
    if (g < NFINE)   fine_cursor[g]   = g * CAP2;
    if (g == 0) *gcur = 0;
    if (g < NN / 8) {                                  // pack 8 depths -> 4-bit classes
        int4 a = *(const int4*)(depth + g * 8);
        int4 b = *(const int4*)(depth + g * 8 + 4);
        CT[g] = ((u32)a.x & 7u)        | (((u32)a.y & 7u) << 4)
              | (((u32)a.z & 7u) << 8) | (((u32)a.w & 7u) << 12)
              | (((u32)b.x & 7u) << 16)| (((u32)b.y & 7u) << 20)
              | (((u32)b.z & 7u) << 24)| (((u32)b.w & 7u) << 28);
    }
    int node = g >> 3, s = g & 7;
    if (depth[node] > ITERS) return;                   // depth-4 rows never read
    float2 f = *(const float2*)(h + (size_t)node * DIM + s * 2);
    hbA[(size_t)node * 8 + s] = pack_bf16x2(f.x, f.y);
    if (s < 2) {
        float2 fc = *(const float2*)(h + (size_t)node * DIM + 16 + s * 2);
        hbC[(size_t)node * 2 + s] = pack_bf16x2(fc.x, fc.y);
    }
}

// ---------------- P1: edges -> 98 coarse regions; CT class gather + dead-src drop ----------------
// item u32 = dlow(11) | src<<11 (18) | cls<<29 (3)
__global__ __launch_bounds__(BLOCK) void p1_split(const int* __restrict__ esrc,
                                                  const int* __restrict__ edst,
                                                  const u32* __restrict__ CT,
                                                  int* __restrict__ coarse_cursor,
                                                  u32* __restrict__ buf1) {
    __shared__ u32 hist[NCOARSE];
    __shared__ u32 lbase[NCOARSE];
    __shared__ u32 gbase[NCOARSE];
    __shared__ u32 lout[TILE1];
    int tid = threadIdx.x;
    int start = blockIdx.x * TILE1;
    if (tid < NCOARSE) hist[tid] = 0;
    __syncthreads();

    int4 d4[2], s4[2];
    #pragma unroll
    for (int q = 0; q < 2; ++q) {
        int e4 = start + (q * BLOCK + tid) * 4;
        d4[q] = *(const int4*)(edst + e4);
        s4[q] = *(const int4*)(esrc + e4);
    }
    int dd[IPT1], ss[IPT1];
    dd[0]=d4[0].x; dd[1]=d4[0].y; dd[2]=d4[0].z; dd[3]=d4[0].w;
    dd[4]=d4[1].x; dd[5]=d4[1].y; dd[6]=d4[1].z; dd[7]=d4[1].w;
    ss[0]=s4[0].x; ss[1]=s4[0].y; ss[2]=s4[0].z; ss[3]=s4[0].w;
    ss[4]=s4[1].x; ss[5]=s4[1].y; ss[6]=s4[1].z; ss[7]=s4[1].w;

    // stage all 8 class gathers from the L2-resident 100KB table
    u32 cls[IPT1];
    #pragma unroll
    for (int k = 0; k < IPT1; ++k)
        cls[k] = (CT[(u32)ss[k] >> 3] >> (((u32)ss[k] & 7u) << 2)) & 7u;
    asm volatile("" :: "v"(cls[0]), "v"(cls[1]), "v"(cls[2]), "v"(cls[3]),
                       "v"(cls[4]), "v"(cls[5]), "v"(cls[6]), "v"(cls[7]));

    u32 rank[IPT1];
    #pragma unroll
    for (int k = 0; k < IPT1; ++k)
        if (cls[k] <= 3u) rank[k] = atomicAdd(&hist[(u32)dd[k] >> 11], 1u);
    __syncthreads();

    // scan the 98-bin histogram (wave 0) -> LDS layout bases
    if (tid < 64) {
        u32 a = hist[tid];
        u32 b = (tid + 64 < NCOARSE) ? hist[tid + 64] : 0u;
        u32 ia = a, ib = b;
        #pragma unroll
        for (int off = 1; off < 64; off <<= 1) {
            u32 ta = (u32)__shfl_up((int)ia, off, 64);
            u32 tb = (u32)__shfl_up((int)ib, off, 64);
            if (tid >= off) { ia += ta; ib += tb; }
        }
        u32 totA = (u32)__shfl((int)ia, 63, 64);
        lbase[tid] = ia - a;
        if (tid + 64 < NCOARSE) lbase[tid + 64] = totA + ib - b;
    }
    __syncthreads();
    if (tid < NCOARSE) {
        u32 cq = hist[tid];
        gbase[tid] = cq ? (u32)atomicAdd((u32*)&coarse_cursor[tid], cq) : 0u;
    }
    #pragma unroll
    for (int k = 0; k < IPT1; ++k)
        if (cls[k] <= 3u)
            lout[lbase[(u32)dd[k] >> 11] + rank[k]] =
                ((u32)dd[k] & 2047u) | ((u32)ss[k] << 11) | (cls[k] << 29);
    __syncthreads();
    int wid = tid >> 6, lane = tid & 63;
    for (int b = wid; b < NCOARSE; b += 4) {
        u32 cq = hist[b], lb = lbase[b], gb = gbase[b];
        for (u32 i = lane; i < cq; i += 64)
            buf1[gb + i] = lout[lb + i];
    }
}

// ---------------- P2: coarse -> fine regions, LDS-staged coalesced flush ----------------
// item u32 = ln(6) | src<<6 (18) | cls<<24 (3)   [(w>>11)<<6 carries src+cls together]
__global__ __launch_bounds__(BLOCK) void p2_split(const u32* __restrict__ buf1,
                                                  const int* __restrict__ coarse_cursor,
                                                  int* __restrict__ fine_cursor,
                                                  u32* __restrict__ buf2) {
    int bid = blockIdx.x;
    int c = bid / NT2P, t = bid - c * NT2P;
    int base  = c * CAP1;
    int end   = coarse_cursor[c];                 // base + kept count
    int start = base + t * TILE;
    if (start >= end) return;

    __shared__ u32 hist[FINE_PER_COARSE];
    __shared__ u32 lbase[FINE_PER_COARSE];
    __shared__ u32 gbase[FINE_PER_COARSE];
    __shared__ u32 lout[TILE];
    int tid = threadIdx.x;
    if (tid < FINE_PER_COARSE) hist[tid] = 0;
    __syncthreads();

    u32 w[IPT];
    #pragma unroll
    for (int q = 0; q < 4; ++q) {
        int i4 = start + (q * BLOCK + tid) * 4;
        if (i4 + 3 < end) {
            uint4 v = *(const uint4*)(buf1 + i4);
            w[q * 4 + 0] = v.x; w[q * 4 + 1] = v.y;
            w[q * 4 + 2] = v.z; w[q * 4 + 3] = v.w;
        } else {
            #pragma unroll
            for (int j = 0; j < 4; ++j) {
                int i = i4 + j;
                w[q * 4 + j] = (i < end) ? buf1[i] : 0xFFFFFFFFu;
            }
        }
    }
    u32 rank[IPT];
    #pragma unroll
    for (int k = 0; k < IPT; ++k)
        if (w[k] != 0xFFFFFFFFu)
            rank[k] = atomicAdd(&hist[(w[k] & 2047u) >> 6], 1u);
    __syncthreads();

    if (tid < 32) {
        u32 a = hist[tid], ia = a;
        #pragma unroll
        for (int off = 1; off < 32; off <<= 1) {
            u32 ta = (u32)__shfl_up((int)ia, off, 32);
            if (tid >= off) ia += ta;
        }
        lbase[tid] = ia - a;
        int f = c * FINE_PER_COARSE + tid;
        gbase[tid] = a ? (u32)atomicAdd((u32*)&fine_cursor[f], a) : 0u;
    }
    __syncthreads();
    #pragma unroll
    for (int k = 0; k < IPT; ++k)
        if (w[k] != 0xFFFFFFFFu)
            lout[lbase[(w[k] & 2047u) >> 6] + rank[k]] = (w[k] & 63u) | ((w[k] >> 11) << 6);
    __syncthreads();
    int wid = tid >> 6, lane = tid & 63;
    for (int b = wid; b < FINE_PER_COARSE; b += 4) {
        u32 cq = hist[b], lb = lbase[b], gb = gbase[b];
        for (u32 i = lane; i < cq; i += 64)
            buf2[gb + i] = lout[lb + i];
    }
}

// ---------------- shared device helpers for gather/GRU ----------------

__device__ __forceinline__ float bl(u32 w) { return __uint_as_float(w << 16); }
__device__ __forceinline__ float bh(u32 w) { return __uint_as_float(w & 0xFFFF0000u); }

__device__ __forceinline__ void acc_half(float* xa, float* xc, uint4 a, u32 c) {
    xa[0]+=bl(a.x); xa[1]+=bh(a.x);
    xa[2]+=bl(a.y); xa[3]+=bh(a.y);
    xa[4]+=bl(a.z); xa[5]+=bh(a.z);
    xa[6]+=bl(a.w); xa[7]+=bh(a.w);
    xc[0]+=bl(c);   xc[1]+=bh(c);
}

__device__ __forceinline__ float fast_sigmoid(float t) {
    return 1.0f / (1.0f + __expf(-t));
}
__device__ __forceinline__ float fast_tanh(float t) {
    t = fminf(fmaxf(t, -15.0f), 15.0f);
    float e2 = __expf(2.0f * t);
    return (e2 - 1.0f) / (e2 + 1.0f);
}

// GRU for 64 nodes on wave 0 (tid<64); x comes from xl (stride XSTRIDE)
__device__ __forceinline__ void gru_body(
    int u, int tid, const float* xl,
    const float* __restrict__ h_in, float* __restrict__ h_out,
    u32* __restrict__ hbA_out, u32* __restrict__ hbC_out,
    int du, int limNext, int isFinal,
    const float* __restrict__ Wz, const float* __restrict__ bWz,
    const float* __restrict__ Uz, const float* __restrict__ bUz,
    const float* __restrict__ Wr, const float* __restrict__ bWr,
    const float* __restrict__ Ur, const float* __restrict__ bUr,
    const float* __restrict__ Wh, const float* __restrict__ bWh,
    const float* __restrict__ Uh, const float* __restrict__ bUh)
{
    float x[DIM], h[DIM];
    #pragma unroll
    for (int k = 0; k < DIM; ++k) x[k] = xl[tid * XSTRIDE + k];
    {
        const float4* hv = (const float4*)(h_in + (size_t)u * DIM);
        float4 a0 = hv[0], a1 = hv[1], a2 = hv[2], a3 = hv[3], a4 = hv[4];
        h[0]=a0.x; h[1]=a0.y; h[2]=a0.z; h[3]=a0.w;
        h[4]=a1.x; h[5]=a1.y; h[6]=a1.z; h[7]=a1.w;
        h[8]=a2.x; h[9]=a2.y; h[10]=a2.z; h[11]=a2.w;
        h[12]=a3.x; h[13]=a3.y; h[14]=a3.z; h[15]=a3.w;
        h[16]=a4.x; h[17]=a4.y; h[18]=a4.z; h[19]=a4.w;
    }

    float z[DIM], rh[DIM];
    #pragma unroll
    for (int j = 0; j < DIM; ++j) {
        float sz = bWz[j] + bUz[j];
        float sr = bWr[j] + bUr[j];
        #pragma unroll
        for (int k = 0; k < DIM; ++k) {
            sz += x[k] * Wz[j * DIM + k];
            sz += h[k] * Uz[j * DIM + k];
            sr += x[k] * Wr[j * DIM + k];
            sr += h[k] * Ur[j * DIM + k];
        }
        z[j]  = fast_sigmoid(sz);
        rh[j] = fast_sigmoid(sr) * h[j];
    }

    float o[DIM];
    #pragma unroll
    for (int j = 0; j < DIM; ++j) {
        float sh = bWh[j] + bUh[j];
        #pragma unroll
        for (int k = 0; k < DIM; ++k) {
            sh += x[k]  * Wh[j * DIM + k];
            sh += rh[k] * Uh[j * DIM + k];
        }
        float hc = fast_tanh(sh);
        o[j] = z[j] * h[j] + (1.0f - z[j]) * hc;
    }

    {
        float4* o4 = (float4*)(h_out + (size_t)u * DIM);
        o4[0] = make_float4(o[0],  o[1],  o[2],  o[3]);
        o4[1] = make_float4(o[4],  o[5],  o[6],  o[7]);
        o4[2] = make_float4(o[8],  o[9],  o[10], o[11]);
        o4[3] = make_float4(o[12], o[13], o[14], o[15]);
        o4[4] = make_float4(o[16], o[17], o[18], o[19]);
    }
    if (!isFinal && du <= limNext) {                 // only rows read next iteration
        u32* rowA = hbA_out + (size_t)u * 8;
        uint4 wA0 = make_uint4(pack_bf16x2(o[0], o[1]),   pack_bf16x2(o[2], o[3]),
                               pack_bf16x2(o[4], o[5]),   pack_bf16x2(o[6], o[7]));
        uint4 wA1 = make_uint4(pack_bf16x2(o[8], o[9]),   pack_bf16x2(o[10], o[11]),
                               pack_bf16x2(o[12], o[13]), pack_bf16x2(o[14], o[15]));
        *(uint4*)rowA       = wA0;
        *(uint4*)(rowA + 4) = wA1;
        *(uint2*)(hbC_out + (size_t)u * 2) =
            make_uint2(pack_bf16x2(o[16], o[17]), pack_bf16x2(o[18], o[19]));
    }
}

// ---------------- PB_GRU: sort fine bucket + it0 gather (from LDS) + it0 GRU, fused ----------------
__global__ __launch_bounds__(BLOCK) void pb_gru(
    const u32* __restrict__ buf2, const int* __restrict__ fine_cursor,
    int* __restrict__ gcur,
    int* __restrict__ ptr, u32* __restrict__ cnt3, u32* __restrict__ ssrc,
    const u32* __restrict__ hbA_in, const u32* __restrict__ hbC_in,
    u32* __restrict__ hbA_out, u32* __restrict__ hbC_out,
    const float* __restrict__ h_in, float* __restrict__ h_out,
    const int* __restrict__ depth,
    const float* __restrict__ Wz, const float* __restrict__ bWz,
    const float* __restrict__ Uz, const float* __restrict__ bUz,
    const float* __restrict__ Wr, const float* __restrict__ bWr,
    const float* __restrict__ Ur, const float* __restrict__ bUr,
    const float* __restrict__ Wh, const float* __restrict__ bWh,
    const float* __restrict__ Uh, const float* __restrict__ bUh)
{
    __shared__ u32 hist[512];
    __shared__ u32 ebase[512];
    __shared__ u32 lout[CAP2];
    __shared__ u32 wsum[4];
    __shared__ int slo;
    __shared__ float xl[64 * XSTRIDE];               // 5376 B
    int tid = threadIdx.x;
    int f = blockIdx.x;
    int base = f * CAP2;
    int end  = fine_cursor[f];
    int cnt  = end - base;
    hist[tid] = 0; hist[tid + 256] = 0;
    __syncthreads();

    // ---- sort phase (counting sort on (node, class)); class carried in item bits 24-26 ----
    u32 w[PIPT];
    #pragma unroll
    for (int q = 0; q < 2; ++q) {
        int i4 = base + (q * BLOCK + tid) * 4;
        if (i4 + 3 < end) {
            uint4 v = *(const uint4*)(buf2 + i4);
            w[q * 4 + 0] = v.x; w[q * 4 + 1] = v.y;
            w[q * 4 + 2] = v.z; w[q * 4 + 3] = v.w;
        } else {
            #pragma unroll
            for (int j = 0; j < 4; ++j) {
                int i = i4 + j;
                w[q * 4 + j] = (i < end) ? buf2[i] : 0xFFFFFFFFu;
            }
        }
    }
    u32 key[PIPT], rank[PIPT];
    #pragma unroll
    for (int k = 0; k < PIPT; ++k) {
        if (w[k] != 0xFFFFFFFFu) {
            u32 cls = (w[k] >> 24) & 7u;
            key[k]  = (w[k] & 63u) * 8u + cls;
            rank[k] = atomicAdd(&hist[key[k]], 1u);
        }
    }
    if (tid == 0) slo = atomicAdd(gcur, cnt);     // reserve packed output space
    __syncthreads();
    {
        u32 s0 = hist[2 * tid], s1 = hist[2 * tid + 1];
        u32 s = s0 + s1;
        int lane = tid & 63, wid = tid >> 6;
        u32 incl = s;
        #pragma unroll
        for (int off = 1; off < 64; off <<= 1) {
            u32 t = __shfl_up((int)incl, off, 64);
            if (lane >= off) incl += t;
        }
        if (lane == 63) wsum[wid] = incl;
        __syncthreads();
        u32 woff = 0;
        for (int w2 = 0; w2 < wid; ++w2) woff += wsum[w2];
        u32 excl = woff + incl - s;
        ebase[2 * tid]     = excl;
        ebase[2 * tid + 1] = excl + s0;
    }
    __syncthreads();
    int lo = slo;
    if (tid < NODES_PER_FINE) {
        u32 base0 = ebase[tid * 8];
        u32 cc1 = ebase[tid * 8 + 2] - base0;
        u32 cc2 = ebase[tid * 8 + 3] - base0;
        u32 cc3 = ebase[tid * 8 + 4] - base0;
        int u = f * NODES_PER_FINE + tid;
        ptr[u]  = lo + (int)base0;
        cnt3[u] = cc1 | (cc2 << 10) | (cc3 << 20);
    }
    #pragma unroll
    for (int k = 0; k < PIPT; ++k) {
        if (w[k] != 0xFFFFFFFFu) lout[ebase[key[k]] + rank[k]] = (w[k] >> 6) & 0x3FFFFu;
    }
    __syncthreads();
    // flush packed list for it1/it2
    for (int j = tid; j < cnt; j += BLOCK) ssrc[lo + j] = lout[j];

    // ---- it0 gather phase: indices straight from LDS lout (original node ids) ----
    int t = tid & 7, team = tid >> 3;                // 32 teams of 8 lanes
    int r = t >> 1, q = t & 1;                       // 4 row slots x 2 half-rows
    #pragma unroll
    for (int rep = 0; rep < 2; ++rep) {
        int nl = team + rep * 32;
        int u = f * NODES_PER_FINE + nl;
        if (depth[u] <= ITERS) {
            int b0 = (int)ebase[nl * 8];
            int d  = (int)(ebase[nl * 8 + 4] - ebase[nl * 8]);   // class<=3 count

            float xa[8], xc[2];
            #pragma unroll
            for (int k = 0; k < 8; ++k) xa[k] = 0.0f;
            xc[0] = 0.0f; xc[1] = 0.0f;

            int e = r;
            for (; e + 12 < d; e += 16) {            // 4 rows in flight per lane
                u32 p0 = lout[b0 + e];
                u32 p1 = lout[b0 + e + 4];
                u32 p2 = lout[b0 + e + 8];
                u32 p3 = lout[b0 + e + 12];
                uint4 a0 = *(const uint4*)(hbA_in + (size_t)p0 * 8 + q * 4);
                uint4 a1 = *(const uint4*)(hbA_in + (size_t)p1 * 8 + q * 4);
                uint4 a2 = *(const uint4*)(hbA_in + (size_t)p2 * 8 + q * 4);
                uint4 a3 = *(const uint4*)(hbA_in + (size_t)p3 * 8 + q * 4);
                u32 cc0 = hbC_in[(size_t)p0 * 2 + q];
                u32 cc1 = hbC_in[(size_t)p1 * 2 + q];
                u32 cc2 = hbC_in[(size_t)p2 * 2 + q];
                u32 cc3 = hbC_in[(size_t)p3 * 2 + q];
                acc_half(xa, xc, a0, cc0);
                acc_half(xa, xc, a1, cc1);
                acc_half(xa, xc, a2, cc2);
                acc_half(xa, xc, a3, cc3);
            }
            for (; e + 4 < d; e += 8) {
                u32 p0 = lout[b0 + e];
                u32 p1 = lout[b0 + e + 4];
                uint4 a0 = *(const uint4*)(hbA_in + (size_t)p0 * 8 + q * 4);
                uint4 a1 = *(const uint4*)(hbA_in + (size_t)p1 * 8 + q * 4);
                u32 cc0 = hbC_in[(size_t)p0 * 2 + q];
                u32 cc1 = hbC_in[(size_t)p1 * 2 + q];
                acc_half(xa, xc, a0, cc0);
                acc_half(xa, xc, a1, cc1);
            }
            if (e < d) {
                u32 p0 = lout[b0 + e];
                uint4 a0 = *(const uint4*)(hbA_in + (size_t)p0 * 8 + q * 4);
                u32 cc0 = hbC_in[(size_t)p0 * 2 + q];
                acc_half(xa, xc, a0, cc0);
            }
            #pragma unroll
            for (int k = 0; k < 8; ++k) {
                xa[k] += __shfl_xor(xa[k], 2, 64);
                xa[k] += __shfl_xor(xa[k], 4, 64);
            }
            xc[0] += __shfl_xor(xc[0], 2, 64); xc[0] += __shfl_xor(xc[0], 4, 64);
            xc[1] += __shfl_xor(xc[1], 2, 64); xc[1] += __shfl_xor(xc[1], 4, 64);

            float* xr = xl + nl * XSTRIDE;
            if (t == 0) {                            // q=0: dims 0-7, 16,17
                #pragma unroll
                for (int k = 0; k < 8; ++k) xr[k] = xa[k];
                xr[16] = xc[0]; xr[17] = xc[1];
            } else if (t == 1) {                     // q=1: dims 8-15, 18,19
                #pragma unroll
                for (int k = 0; k < 8; ++k) xr[8 + k] = xa[k];
                xr[18] = xc[0]; xr[19] = xc[1];
            }
        }
    }
    __syncthreads();
    if (tid >= 64) return;                           // waves 1-3 retire

    // ---- it0 GRU phase ----
    int u = f * NODES_PER_FINE + tid;
    int du = depth[u];
    if (du > ITERS) return;                          // not final: no zero-fill
    gru_body(u, tid, xl, h_in, h_out, hbA_out, hbC_out, du, 2, 0,
             Wz, bWz, Uz, bUz, Wr, bWr, Ur, bUr, Wh, bWh, Uh, bUh);
}

// ---------------- fused iteration (it1/it2): gather from global ssrc + GRU ----------------

__global__ __launch_bounds__(BLOCK) void grnn_iter(
    const u32* __restrict__ hbA_in, const u32* __restrict__ hbC_in,
    u32* __restrict__ hbA_out, u32* __restrict__ hbC_out,
    const float* __restrict__ h_in, float* __restrict__ h_out,
    const int* __restrict__ depth, const int* __restrict__ ptr,
    const u32* __restrict__ cnt3, const u32* __restrict__ ssrc,
    const float* __restrict__ Wz, const float* __restrict__ bWz,
    const float* __restrict__ Uz, const float* __restrict__ bUz,
    const float* __restrict__ Wr, const float* __restrict__ bWr,
    const float* __restrict__ Ur, const float* __restrict__ bUr,
    const float* __restrict__ Wh, const float* __restrict__ bWh,
    const float* __restrict__ Uh, const float* __restrict__ bUh,
    int lim, int limNext, int shift, int isFinal)
{
    __shared__ float xl[64 * XSTRIDE];               // 5376 B
    int tid = threadIdx.x;
    int t = tid & 7, team = tid >> 3;                // 32 teams of 8 lanes
    int r = t >> 1, q = t & 1;                       // 4 row slots x 2 half-rows

    #pragma unroll
    for (int rep = 0; rep < 2; ++rep) {
        int nl = team + rep * 32;
        int u = blockIdx.x * 64 + nl;
        if (depth[u] <= lim) {
            int p = ptr[u];
            int d = (int)((cnt3[u] >> shift) & 1023u);

            float xa[8], xc[2];
            #pragma unroll
            for (int k = 0; k < 8; ++k) xa[k] = 0.0f;
            xc[0] = 0.0f; xc[1] = 0.0f;

            int e = r;
            for (; e + 12 < d; e += 16) {            // 4 rows in flight per lane
                u32 p0 = ssrc[p + e];
                u32 p1 = ssrc[p + e + 4];
                u32 p2 = ssrc[p + e + 8];
                u32 p3 = ssrc[p + e + 12];
                uint4 a0 = *(const uint4*)(hbA_in + (size_t)p0 * 8 + q * 4);
                uint4 a1 = *(const uint4*)(hbA_in + (size_t)p1 * 8 + q * 4);
                uint4 a2 = *(const uint4*)(hbA_in + (size_t)p2 * 8 + q * 4);
                uint4 a3 = *(const uint4*)(hbA_in + (size_t)p3 * 8 + q * 4);
                u32 cc0 = hbC_in[(size_t)p0 * 2 + q];
                u32 cc1 = hbC_in[(size_t)p1 * 2 + q];
                u32 cc2 = hbC_in[(size_t)p2 * 2 + q];
                u32 cc3 = hbC_in[(size_t)p3 * 2 + q];
                acc_half(xa, xc, a0, cc0);
                acc_half(xa, xc, a1, cc1);
                acc_half(xa, xc, a2, cc2);
                acc_half(xa, xc, a3, cc3);
            }
            for (; e + 4 < d; e += 8) {
                u32 p0 = ssrc[p + e];
                u32 p1 = ssrc[p + e + 4];
                uint4 a0 = *(const uint4*)(hbA_in + (size_t)p0 * 8 + q * 4);
                uint4 a1 = *(const uint4*)(hbA_in + (size_t)p1 * 8 + q * 4);
                u32 cc0 = hbC_in[(size_t)p0 * 2 + q];
                u32 cc1 = hbC_in[(size_t)p1 * 2 + q];
                acc_half(xa, xc, a0, cc0);
                acc_half(xa, xc, a1, cc1);
            }
            if (e < d) {
                u32 p0 = ssrc[p + e];
                uint4 a0 = *(const uint4*)(hbA_in + (size_t)p0 * 8 + q * 4);
                u32 cc0 = hbC_in[(size_t)p0 * 2 + q];
                acc_half(xa, xc, a0, cc0);
            }
            #pragma unroll
            for (int k = 0; k < 8; ++k) {
                xa[k] += __shfl_xor(xa[k], 2, 64);
                xa[k] += __shfl_xor(xa[k], 4, 64);
            }
            xc[0] += __shfl_xor(xc[0], 2, 64); xc[0] += __shfl_xor(xc[0], 4, 64);
            xc[1] += __shfl_xor(xc[1], 2, 64); xc[1] += __shfl_xor(xc[1], 4, 64);

            float* xr = xl + nl * XSTRIDE;
            if (t == 0) {
                #pragma unroll
                for (int k = 0; k < 8; ++k) xr[k] = xa[k];
                xr[16] = xc[0]; xr[17] = xc[1];
            } else if (t == 1) {
                #pragma unroll
                for (int k = 0; k < 8; ++k) xr[8 + k] = xa[k];
                xr[18] = xc[0]; xr[19] = xc[1];
            }
        }
    }
    __syncthreads();
    if (tid >= 64) return;                           // waves 1-3 retire

    int u = blockIdx.x * 64 + tid;
    int du = depth[u];
    if (du > lim) {
        if (isFinal) {
            float4 z4 = make_float4(0.f, 0.f, 0.f, 0.f);
            float4* o4 = (float4*)(h_out + (size_t)u * DIM);
            #pragma unroll
            for (int qq = 0; qq < 5; ++qq) o4[qq] = z4;
        }
        return;
    }
    gru_body(u, tid, xl, h_in, h_out, hbA_out, hbC_out, du, limNext, isFinal,
             Wz, bWz, Uz, bUz, Wr, bWr, Ur, bUr, Wh, bWh, Uh, bUh);
}

// ---------------- launch ----------------

extern "C" void kernel_launch(void* const* d_in, const int* in_sizes, int n_in,
                              void* d_out, int out_size, void* d_ws, size_t ws_size,
                              hipStream_t stream) {
    const float* h0    = (const float*)d_in[0];
    const int*   depth = (const int*)d_in[1];
    const int*   esrc  = (const int*)d_in[2];
    const int*   edst  = (const int*)d_in[3];
    const float* Wz  = (const float*)d_in[4];  const float* bWz = (const float*)d_in[5];
    const float* Uz  = (const float*)d_in[6];  const float* bUz = (const float*)d_in[7];
    const float* Wr  = (const float*)d_in[8];  const float* bWr = (const float*)d_in[9];
    const float* Ur  = (const float*)d_in[10]; const float* bUr = (const float*)d_in[11];
    const float* Wh  = (const float*)d_in[12]; const float* bWh = (const float*)d_in[13];
    const float* Uh  = (const float*)d_in[14]; const float* bUh = (const float*)d_in[15];
    float* out = (float*)d_out;

    // workspace layout (int32 units)
    int* W = (int*)d_ws;
    u32*  CT            = (u32*)(W + 0);           // 25000 (100 KB class table)
    int*  gcur          = W + 25024;               // 1 (+pad)
    int*  coarse_cursor = W + 25088;               // 98 (+pad)
    int*  fine_cursor   = W + 25216;               // 3125 (+pad)
    int*  ptr           = W + 28416;               // NN
    u32*  cnt3          = (u32*)(W + 228416);      // NN
    u32*  buf1          = (u32*)(W + 428416);      // 98*CAP1 = 5,619,712 (later packed ssrc)
    u32*  buf2          = buf1 + (size_t)NCOARSE * CAP1;   // 3125*CAP2 = 6,400,000
    float* h1           = (float*)(buf2 + (size_t)NFINE * CAP2); // NN*DIM
    u32*  hbA0          = (u32*)(h1 + (size_t)NN * DIM);  // NN*8 (node-id rows)
    u32*  hbC0          = hbA0 + (size_t)NN * 8;          // NN*2
    u32*  hbA1          = hbC0 + (size_t)NN * 2;          // NN*8
    u32*  hbC1          = hbA1 + (size_t)NN * 8;          // NN*2
    u32*  ssrc          = buf1;                    // packed output of pb (node ids)

    setup   <<<(NN * 8) / BLOCK, BLOCK, 0, stream>>>(h0, depth, hbA0, hbC0, CT,
                                                     coarse_cursor, fine_cursor, gcur);
    p1_split<<<EE / TILE1, BLOCK, 0, stream>>>(esrc, edst, CT, coarse_cursor, buf1);
    p2_split<<<NCOARSE * NT2P, BLOCK, 0, stream>>>(buf1, coarse_cursor, fine_cursor, buf2);

    // pb + it0 fused: sort, write ssrc/ptr/cnt3 for it1/2, gather from LDS, GRU
    pb_gru  <<<NFINE, BLOCK, 0, stream>>>(buf2, fine_cursor, gcur, ptr, cnt3, ssrc,
        hbA0, hbC0, hbA1, hbC1, h0, h1, depth,
        Wz, bWz, Uz, bUz, Wr, bWr, Ur, bUr, Wh, bWh, Uh, bUh);

    // it1: lim=2, shift=10 (c_le2); reads hb1, writes hb0 for depth<=1; h in-place
    grnn_iter<<<NN / 64, BLOCK, 0, stream>>>(hbA1, hbC1, hbA0, hbC0, h1, h1,
        depth, ptr, cnt3, ssrc,
        Wz, bWz, Uz, bUz, Wr, bWr, Ur, bUr, Wh, bWh, Uh, bUh, 2, 1, 10, 0);
    // it2: lim=1, shift=0 (c_le1); final -> write out, zero inactive
    grnn_iter<<<NN / 64, BLOCK, 0, stream>>>(hbA0, hbC0, hbA1, hbC1, h1, out,
        depth, ptr, cnt3, ssrc,
        Wz, bWz, Uz, bUz, Wr, bWr, Ur, bUr, Wh, bWh, Uh, bUh, 1, 0, 0, 1);
}